// Round 4
// baseline (82.027 us; speedup 1.0000x reference)
//
#include <hip/hip_runtime.h>
#include <stdint.h>

typedef __attribute__((ext_vector_type(4))) int i32x4;

__device__ inline float wave_max(float v){ for(int o=32;o;o>>=1) v=fmaxf(v,__shfl_xor(v,o)); return v; }
__device__ inline float wave_min(float v){ for(int o=32;o;o>>=1) v=fminf(v,__shfl_xor(v,o)); return v; }
__device__ inline int   wave_sum(int v){ for(int o=32;o;o>>=1) v+=__shfl_xor(v,o); return v; }

__device__ inline void gload16(const void* g, void* l){
  __builtin_amdgcn_global_load_lds((const __attribute__((address_space(1))) char*)g,
                                   (__attribute__((address_space(3))) char*)l, 16, 0, 0);
}

// stage 1: per-block max -> partials[blockIdx.x]  (no atomics)
__global__ void k_xmax_partial(const float* __restrict__ x, long long n4,
                               float* __restrict__ partials){
  long long i = (long long)blockIdx.x*blockDim.x + threadIdx.x;
  long long stride = (long long)gridDim.x*blockDim.x;
  const float4* x4 = (const float4*)x;
  float m = 0.f;
  for(; i < n4; i += stride){
    float4 v = x4[i];
    m = fmaxf(m, fmaxf(fmaxf(v.x,v.y),fmaxf(v.z,v.w)));
  }
  m = wave_max(m);
  __shared__ float sm[4];
  int lane = threadIdx.x & 63, wid = threadIdx.x >> 6;
  if(lane==0) sm[wid] = m;
  __syncthreads();
  if(threadIdx.x==0)
    partials[blockIdx.x] = fmaxf(fmaxf(sm[0],sm[1]),fmaxf(sm[2],sm[3]));
}

// stage 2: one block reduces nPart partials
__global__ void k_xmax_final(const float* __restrict__ partials, int nPart,
                             uint32_t* __restrict__ xmax_bits){
  float m = 0.f;
  for(int i = threadIdx.x; i < nPart; i += 256) m = fmaxf(m, partials[i]);
  m = wave_max(m);
  __shared__ float sm[4];
  int lane = threadIdx.x & 63, wid = threadIdx.x >> 6;
  if(lane==0) sm[wid] = m;
  __syncthreads();
  if(threadIdx.x==0)
    *xmax_bits = __float_as_uint(fmaxf(fmaxf(sm[0],sm[1]),fmaxf(sm[2],sm[3])));
}

// one block (256 thr) per output channel row; din must be 2048
__global__ void k_wstat(const float* __restrict__ w, const float* __restrict__ bias,
                        const int* __restrict__ wbit, const uint32_t* __restrict__ xmax_bits,
                        float* __restrict__ scale_w, float* __restrict__ zp_w,
                        float* __restrict__ winv,
                        int* __restrict__ cint, char* __restrict__ qw, int din){
  int row = blockIdx.x, tid = threadIdx.x;
  int lane = tid & 63, wid = tid >> 6;
  const float4* wr4 = (const float4*)(w + (long long)row*din);
  float4 a = wr4[tid*2], b = wr4[tid*2+1];
  float v[8] = {a.x,a.y,a.z,a.w,b.x,b.y,b.z,b.w};
  float mn = v[0], mx = v[0];
  for(int j=1;j<8;j++){ mn=fminf(mn,v[j]); mx=fmaxf(mx,v[j]); }
  float wmn = wave_min(mn), wmx = wave_max(mx);
  __shared__ float smn[4], smx[4];
  __shared__ float s_sw, s_zp; __shared__ int s_qb;
  if(lane==0){ smn[wid]=wmn; smx[wid]=wmx; }
  __syncthreads();
  if(tid==0){
    float fmn = fminf(fminf(smn[0],smn[1]),fminf(smn[2],smn[3]));
    float fmx = fmaxf(fmaxf(smx[0],smx[1]),fmaxf(smx[2],smx[3]));
    int n = 1 << *wbit;
    float nm1 = (float)(n-1);
    float xmax = __uint_as_float(*xmax_bits);
    float sx = __fdiv_rn(nm1, fmaxf(xmax, 1e-8f));
    float rng = __fsub_rn(fmx, fmn);
    float rngc = fmaxf(rng, 1e-8f);
    float sw = __fdiv_rn(nm1, rngc);
    float zp = __fmul_rn(sw, fmn);
    float qbf = rintf(__fmul_rn(__fmul_rn(bias[row], sw), sx));
    qbf = fminf(fmaxf(qbf, -(float)(n+1)), (float)n);
    s_sw = sw; s_zp = zp; s_qb = (int)qbf;
    scale_w[row] = sw; zp_w[row] = zp;
    winv[row] = __fdiv_rn(rngc, nm1);     // 1/scale_w, one rounding
  }
  __syncthreads();
  float sw = s_sw, zp = s_zp;
  int qsum = 0; uint32_t lo = 0, hi = 0;
  for(int j=0;j<8;j++){
    int q = (int)rintf(__fsub_rn(__fmul_rn(sw, v[j]), zp));   // exact replication, no fma
    qsum += q;
    uint32_t u = (uint32_t)((q - 128) & 0xff);
    if(j<4) lo |= u << (8*j); else hi |= u << (8*(j-4));
  }
  uint32_t* qrow = (uint32_t*)(qw + (long long)row*din);
  qrow[tid*2] = lo; qrow[tid*2+1] = hi;
  int wsum = wave_sum(qsum);
  __shared__ int ssum[4];
  if(lane==0) ssum[wid] = wsum;
  __syncthreads();
  if(tid==0){
    int Sb = ssum[0]+ssum[1]+ssum[2]+ssum[3];
    cint[row] = 128*Sb - 128*128*din + s_qb;
  }
}

// one block (256 thr) per token row
__global__ void k_xquant(const float* __restrict__ x, const int* __restrict__ wbit,
                         const uint32_t* __restrict__ xmax_bits,
                         char* __restrict__ qx, int* __restrict__ Sa, int din){
  int row = blockIdx.x, tid = threadIdx.x;
  int lane = tid & 63, wid = tid >> 6;
  int n = 1 << *wbit;
  float nm1 = (float)(n-1);
  float sx = __fdiv_rn(nm1, fmaxf(__uint_as_float(*xmax_bits), 1e-8f));
  const float4* xr4 = (const float4*)(x + (long long)row*din);
  float4 a = xr4[tid*2], b = xr4[tid*2+1];
  float v[8] = {a.x,a.y,a.z,a.w,b.x,b.y,b.z,b.w};
  int qsum = 0; uint32_t lo = 0, hi = 0;
  for(int j=0;j<8;j++){
    int q = (int)rintf(__fmul_rn(sx, v[j]));
    qsum += q;
    uint32_t u = (uint32_t)((q - 128) & 0xff);
    if(j<4) lo |= u << (8*j); else hi |= u << (8*(j-4));
  }
  uint32_t* qrow = (uint32_t*)(qx + (long long)row*din);
  qrow[tid*2] = lo; qrow[tid*2+1] = hi;
  int wsum = wave_sum(qsum);
  __shared__ int ssum[4];
  if(lane==0) ssum[wid] = wsum;
  __syncthreads();
  if(tid==0) Sa[row] = ssum[0]+ssum[1]+ssum[2]+ssum[3];
}

// ============ 256x128 tri-buffered i8 GEMM, 4 waves, 2 blocks/CU ============
// BM=256 (qx rows), BN=128 (qw rows), BK=64 bytes. 4 waves (2Mx2N), per-wave
// 128x64 out (identical fragment addressing + zero-conflict chunk swizzle as
// the verified round-3 kernel). LDS: 3 slots x (A 16K + B 8K) = 72 KiB ->
// 2 blocks/CU (independent barrier domains hide each other's stalls, m114).
// ONE barrier per K-tile: slot written during tile t is (t+2)%3, untouched by
// tiles t,t+1; reads of slot t are lgkm-drained before MFMA; vmcnt(6) keeps
// tile t+2's 6 loads in flight across the barrier (never 0 in main loop).
#define ASLOT 16384
#define BSLOT 8192
#define SLOT  (ASLOT + BSLOT)

__global__ __launch_bounds__(256, 2) void k_gemm(
    const char* __restrict__ qx, const char* __restrict__ qw,
    const int* __restrict__ Sa, const int* __restrict__ cint,
    const float* __restrict__ winv, const float* __restrict__ zp_w,
    const int* __restrict__ wbit, const uint32_t* __restrict__ xmax_bits,
    float* __restrict__ out, int T, int dout, int din){
  extern __shared__ char lds[];   // 3 * SLOT = 73728 B
  const int tid = threadIdx.x, lane = tid & 63, wid = tid >> 6;
  const int wr = (wid >> 1) * 128, wc = (wid & 1) * 64;
  const int tileN = blockIdx.x, tileM = blockIdx.y;

  // ---- staging: 6 chunk-loads/thread/K-tile (A:4, B:2) ----
  // chunk idx = j*256+tid; row = j*64 + (tid>>2); c2 = tid&3;
  // global source pre-swizzled: c2 ^ ((row>>1)&3)  (write side, rule #21)
  const int rbase = tid >> 2, c2 = tid & 3;
  const char* aG[4]; const char* bG[2]; int ldA[4], ldB[2];
  #pragma unroll
  for(int j=0;j<4;j++){
    int row = j*64 + rbase;
    int sc = c2 ^ ((row >> 1) & 3);
    aG[j] = qx + ((long long)tileM*256 + row)*din + sc*16;
    ldA[j] = (j*256 + tid)*16;
  }
  #pragma unroll
  for(int j=0;j<2;j++){
    int row = j*64 + rbase;
    int sc = c2 ^ ((row >> 1) & 3);
    bG[j] = qw + ((long long)tileN*128 + row)*din + sc*16;
    ldB[j] = ASLOT + (j*256 + tid)*16;
  }

  // ---- ds_read addressing (swizzled chunk, proven zero-conflict) ----
  const int physo = (((lane >> 4) ^ ((lane >> 1) & 3)) * 16);
  const int arowL = wr + (lane & 15);   // + mh*64 + mi*16
  const int browL = wc + (lane & 15);   // + ni*16

  i32x4 acc[8][4] = {};
  const int nk = din / 64;

  // ---- prologue: stage tiles 0,1 (12 loads); wait tile 0; barrier ----
  {
    char* s0 = lds; char* s1 = lds + SLOT;
    #pragma unroll
    for(int j=0;j<4;j++) gload16(aG[j], s0 + ldA[j]);
    #pragma unroll
    for(int j=0;j<2;j++) gload16(bG[j], s0 + ldB[j]);
    #pragma unroll
    for(int j=0;j<4;j++) gload16(aG[j] + 64, s1 + ldA[j]);
    #pragma unroll
    for(int j=0;j<2;j++) gload16(bG[j] + 64, s1 + ldB[j]);
  }
  asm volatile("s_waitcnt vmcnt(6)" ::: "memory");
  __builtin_amdgcn_s_barrier();

  for(int kt = 0; kt < nk; ++kt){
    char* As = lds + (kt % 3)*SLOT;
    char* Bs = As + ASLOT;

    // issue next-next tile's stage first (overlaps whole tile)
    if(kt + 2 < nk){
      char* Sn = lds + ((kt + 2) % 3)*SLOT;
      const long long ko = (long long)(kt + 2) * 64;
      #pragma unroll
      for(int j=0;j<4;j++) gload16(aG[j] + ko, Sn + ldA[j]);
      #pragma unroll
      for(int j=0;j<2;j++) gload16(bG[j] + ko, Sn + ldB[j]);
    }

    i32x4 bf[4], af[8];
    #pragma unroll
    for(int ni=0; ni<4; ++ni) bf[ni] = *(const i32x4*)(Bs + (browL + ni*16)*64 + physo);
    #pragma unroll
    for(int mi=0; mi<8; ++mi) af[mi] = *(const i32x4*)(As + (arowL + mi*16)*64 + physo);

    __builtin_amdgcn_s_setprio(1);
    #pragma unroll
    for(int mi=0; mi<8; ++mi)
      #pragma unroll
      for(int ni=0; ni<4; ++ni)
        acc[mi][ni] = __builtin_amdgcn_mfma_i32_16x16x64_i8(af[mi], bf[ni], acc[mi][ni], 0, 0, 0);
    __builtin_amdgcn_s_setprio(0);

    if(kt < nk - 2) asm volatile("s_waitcnt vmcnt(6)" ::: "memory");
    else            asm volatile("s_waitcnt vmcnt(0)" ::: "memory");
    __builtin_amdgcn_s_barrier();
  }

  // ---- epilogue: out = ((acc + 128*sa + ci) + zp*sa) * (1/sx) * (1/sw) ----
  const float nm1 = (float)((1 << *wbit) - 1);
  const float xmaxc = fmaxf(__uint_as_float(*xmax_bits), 1e-8f);
  const float inv_sx = __fdiv_rn(xmaxc, nm1);
  const int colL = tileN*128 + wc + (lane & 15);
  const int rowL = tileM*256 + wr + ((lane >> 4) * 4);
  float invc[4], zp4[4]; int ci4[4];
  #pragma unroll
  for(int ni=0; ni<4; ++ni){
    int o = colL + ni*16;
    invc[ni] = __fmul_rn(winv[o], inv_sx);
    zp4[ni]  = zp_w[o];
    ci4[ni]  = cint[o];
  }
  #pragma unroll
  for(int mi=0; mi<8; ++mi){
    int rb = rowL + mi*16;
    int sav[4];
    #pragma unroll
    for(int r=0; r<4; ++r) sav[r] = Sa[rb + r];
    #pragma unroll
    for(int ni=0; ni<4; ++ni){
      #pragma unroll
      for(int r=0; r<4; ++r){
        int iv = acc[mi][ni][r] + 128*sav[r] + ci4[ni];
        float f = (float)iv + zp4[ni]*(float)sav[r];
        out[(long long)(rb + r)*dout + colL + ni*16] = __fmul_rn(f, invc[ni]);
      }
    }
  }
}

extern "C" void kernel_launch(void* const* d_in, const int* in_sizes, int n_in,
                              void* d_out, int out_size, void* d_ws, size_t ws_size,
                              hipStream_t stream){
  const float* x    = (const float*)d_in[0];
  const float* w    = (const float*)d_in[1];
  const float* bias = (const float*)d_in[2];
  const int*   wbit = (const int*)d_in[3];
  int dout = in_sizes[2];
  int din  = in_sizes[1] / dout;
  int T    = in_sizes[0] / din;

  const int NPART = 2048;
  char* ws = (char*)d_ws;
  uint32_t* xmax_bits = (uint32_t*)ws;
  size_t off = 256;
  float* partials = (float*)(ws + off); off += 4*(size_t)NPART;
  float* scale_w = (float*)(ws + off); off += 4*(size_t)dout;
  float* zp_w    = (float*)(ws + off); off += 4*(size_t)dout;
  float* winv    = (float*)(ws + off); off += 4*(size_t)dout;
  int*   cint    = (int*)(ws + off);   off += 4*(size_t)dout;
  int*   Sa      = (int*)(ws + off);   off += 4*(size_t)T;
  off = (off + 255) & ~(size_t)255;
  char*  qw      = ws + off;           off += (size_t)dout*din;
  char*  qx      = ws + off;           off += (size_t)T*din;

  long long n4 = (long long)T*din/4;
  k_xmax_partial<<<NPART, 256, 0, stream>>>(x, n4, partials);
  k_xmax_final<<<1, 256, 0, stream>>>(partials, NPART, xmax_bits);
  k_wstat<<<dout, 256, 0, stream>>>(w, bias, wbit, xmax_bits, scale_w, zp_w, winv, cint, qw, din);
  k_xquant<<<T, 256, 0, stream>>>(x, wbit, xmax_bits, qx, Sa, din);
  dim3 grid(dout/128, T/256);
  k_gemm<<<grid, 256, 3*SLOT, stream>>>(qx, qw, Sa, cint, winv, zp_w, wbit, xmax_bits,
                                        (float*)d_out, T, dout, din);
}